// Round 1
// 197.165 us; speedup vs baseline: 1.0130x; 1.0130x over previous
//
#include <hip/hip_runtime.h>
#include <hip/hip_bf16.h>
#include <cstdint>

// Problem (all inputs/outputs fp32):
//   out[8192][2048] = X[8192][2048] @ Weff[2048][2048]
//   Weff[k][n] = W[k][n] + SCALE * sum_r A[k][r]*Bk[r][n], SCALE = 4/4 = 1.0
//
// Pipeline (2 launches):
//   prep_all: [blocks 0..8191] fp32 X -> bf16 Xb (d_ws)
//             [blocks 8192..9215] fp32 (W + A@Bk)^T -> bf16 Wt [N][K]
//   gemm_8ph: 256x256 tile, BK=64, 8 waves (2Mx4N), 8-phase schedule with
//             counted vmcnt(8) (never drained to 0 in the main loop),
//             setprio(1) around each 16-MFMA cluster, 128 KiB LDS double
//             buffer, XOR-chunk swizzle p = c ^ (row&7) (bank-conflict-free,
//             verified R3: SQ_LDS_BANK_CONFLICT = 0), bijective XCD patch
//             swizzle (per-XCD L2 working set ~12 MB).
//   Region-retirement ledger (phase order q(0,0),(0,1),(1,0),(1,1) per tile;
//   A-frags reused across the two qn phases, so A halves are LDS-read in one
//   phase only):
//     buf0 (tile 2j, phases P1-P4): Ah0 free@P2, Bh0 free@P4, Ah1 free@P4,
//     Bh1 free@P5; buf1 (tile 2j+1, P5-P8): Ah0@P6, Bh0/Ah1@P8, Bh1@P1'.
//   Stage issue slots: P1: (2j+1).Bh1 | P2: (2j+2).Ah0 | P4: (2j+2).Bh0+Ah1 |
//     P5: (2j+2).Bh1 | P6: (2j+3).Ah0 | P8: (2j+3).Bh0+Ah1.
//   Waits vmcnt(8) at P1,P4,P5,P8 guarantee (at fenced group granularity)
//   each phase's needed half-tiles landed one phase before they are ds_read.
//   Last iteration peeled: waits 8 -> 2 -> 0, no staging past K.
//   Round-4 lesson kept: do NOT read fp32 X inside the gemm.

using bf16 = __hip_bfloat16;
typedef __attribute__((ext_vector_type(8))) __bf16 bf16x8;
typedef __attribute__((ext_vector_type(4))) float f32x4;

constexpr int Mdim = 8192;   // B*S
constexpr int Ndim = 2048;   // NH*HD
constexpr int Kdim = 2048;   // H
constexpr float SCALE = 1.0f;  // ALPHA/RANK = 4/4

constexpr int BM = 256, BN = 256, BK = 64;
constexpr int NT2 = Kdim / (2 * BK);                   // 16 iterations
constexpr int CVT_BLOCKS = (Mdim * Kdim) / (256 * 8);  // 8192
constexpr int PREP_BLOCKS = (Ndim / 64) * (Kdim / 64); // 1024

__device__ __forceinline__ void gload_lds16(const void* g, void* l) {
  __builtin_amdgcn_global_load_lds(
      (const __attribute__((address_space(1))) uint32_t*)g,
      (__attribute__((address_space(3))) uint32_t*)l,
      16, 0, 0);
}

// ------------- prep_all: cvt_x (blocks<8192) + Weff^T build --------------
__global__ void prep_all(const float* __restrict__ X,
                         const float* __restrict__ W,
                         const float* __restrict__ A,
                         const float* __restrict__ Bk,
                         uint16_t* __restrict__ Xb,
                         uint16_t* __restrict__ Wt) {
  __shared__ float tile[64][65];  // used by prep part only (+1 pad)

  if (blockIdx.x < CVT_BLOCKS) {
    // ---- fp32 -> bf16, 8 elems/thread, float4 loads ----
    const int i = blockIdx.x * blockDim.x + threadIdx.x;
    const float4* Xv = (const float4*)X;
    float4 a = Xv[i * 2 + 0];
    float4 b = Xv[i * 2 + 1];
    uint16_t o[8];
    o[0] = __bfloat16_as_ushort(__float2bfloat16(a.x));
    o[1] = __bfloat16_as_ushort(__float2bfloat16(a.y));
    o[2] = __bfloat16_as_ushort(__float2bfloat16(a.z));
    o[3] = __bfloat16_as_ushort(__float2bfloat16(a.w));
    o[4] = __bfloat16_as_ushort(__float2bfloat16(b.x));
    o[5] = __bfloat16_as_ushort(__float2bfloat16(b.y));
    o[6] = __bfloat16_as_ushort(__float2bfloat16(b.z));
    o[7] = __bfloat16_as_ushort(__float2bfloat16(b.w));
    *reinterpret_cast<uint4*>(Xb + (size_t)i * 8) = *reinterpret_cast<uint4*>(o);
  } else {
    // ---- Weff^T = (W + A@Bk)^T, [N][K] bf16 ----
    const int pid = blockIdx.x - CVT_BLOCKS;       // 0..1023
    const int tx = threadIdx.x & 63;
    const int ty = threadIdx.x >> 6;
    const int n0 = (pid & 31) * 64, k0 = (pid >> 5) * 64;

    const int n = n0 + tx;
    const float b0 = Bk[0 * Ndim + n];
    const float b1 = Bk[1 * Ndim + n];
    const float b2 = Bk[2 * Ndim + n];
    const float b3 = Bk[3 * Ndim + n];

    for (int i = ty; i < 64; i += 4) {
      const int k = k0 + i;
      float w = W[(size_t)k * Ndim + n];
      w += SCALE * (A[k * 4 + 0] * b0 + A[k * 4 + 1] * b1 +
                    A[k * 4 + 2] * b2 + A[k * 4 + 3] * b3);
      tile[tx][i] = w;                       // transposed into LDS
    }
    __syncthreads();
    for (int i = ty; i < 64; i += 4) {
      Wt[(size_t)(n0 + i) * Kdim + (k0 + tx)] =
          __bfloat16_as_ushort(__float2bfloat16(tile[i][tx]));
    }
  }
}

// ---------------- main GEMM: C = Xb @ Weff (Wt is Weff^T, K-major) --------
#define FENCE() asm volatile("" ::: "memory")
#define VMW(N)  asm volatile("s_waitcnt vmcnt(" #N ")" ::: "memory")
#define PMID()                                                                 \
  do {                                                                         \
    FENCE();                                                                   \
    __builtin_amdgcn_s_barrier();                                              \
    asm volatile("s_waitcnt lgkmcnt(0)" ::: "memory");                         \
  } while (0)
#define PEND()                                                                 \
  do {                                                                         \
    FENCE();                                                                   \
    __builtin_amdgcn_s_barrier();                                              \
    FENCE();                                                                   \
  } while (0)

__global__ __launch_bounds__(512, 2) void gemm_8ph(
    const uint16_t* __restrict__ X, const uint16_t* __restrict__ Wt,
    float* __restrict__ out) {
  // LDS: [A0 | B0 | A1 | B1], 16384 uint16 each = 128 KiB total.
  __shared__ uint16_t lds[65536];

  const int t = threadIdx.x;
  const int wave = t >> 6, lane = t & 63;
  const int wm = wave >> 2, wn = wave & 3;   // 2 x 4 wave grid
  const int l15 = lane & 15, kg = lane >> 4;
  const int sw = l15 & 7;

  // Bijective XCD patch swizzle: 256 blocks, 8 XCDs x 32 blocks.
  // Each XCD: 4 by-panels (4 MB of Xb) x 8 bx-panels (all Wt, 8 MB).
  const int lid = blockIdx.x;                 // 0..255
  const int xcd = lid & 7, loc = lid >> 3;    // loc 0..31
  const int by = xcd * 4 + (loc & 3);         // 0..31
  const int bx = loc >> 2;                    // 0..7
  const int m0 = by * BM, n0 = bx * BN;

  const uint16_t* Ag = X + (size_t)m0 * Kdim;
  const uint16_t* Bg = Wt + (size_t)n0 * Kdim;

  // staging geometry: slot = 8 rows x 64 cols (1 KB); wave w owns slots
  // {2w, 2w+1} of each 128-row half-tile. Source chunk col is XOR-swizzled
  // so the linear LDS dest holds phys chunk p = c ^ (row&7).
  const int r8 = lane >> 3;
  const int gc = (lane & 7) ^ r8;
  const int slot0 = wave * 2, slot1 = slot0 + 1;
  const size_t go0 = (size_t)(slot0 * 8 + r8) * Kdim + gc * 8;
  const size_t go1 = (size_t)(slot1 * 8 + r8) * Kdim + gc * 8;

  // per-lane LDS element offsets for frag reads (per k-step s2)
  int aE[2], bE[2];
#pragma unroll
  for (int s2 = 0; s2 < 2; ++s2) {
    const int p = (s2 * 4 + kg) ^ sw;
    aE[s2] = (wm * 64 + l15) * 64 + p * 8;
    bE[s2] = (wn * 32 + l15) * 64 + p * 8;
  }

#define STAGE_A(buf, h, kt)                                                    \
  do {                                                                         \
    gload_lds16(Ag + go0 + (size_t)(h) * 128 * Kdim + (kt),                    \
                &lds[(buf) * 32768 + (h) * 8192 + slot0 * 512]);               \
    gload_lds16(Ag + go1 + (size_t)(h) * 128 * Kdim + (kt),                    \
                &lds[(buf) * 32768 + (h) * 8192 + slot1 * 512]);               \
  } while (0)
#define STAGE_B(buf, h, kt)                                                    \
  do {                                                                         \
    gload_lds16(Bg + go0 + (size_t)(h) * 128 * Kdim + (kt),                    \
                &lds[(buf) * 32768 + 16384 + (h) * 8192 + slot0 * 512]);       \
    gload_lds16(Bg + go1 + (size_t)(h) * 128 * Kdim + (kt),                    \
                &lds[(buf) * 32768 + 16384 + (h) * 8192 + slot1 * 512]);       \
  } while (0)

  bf16x8 a[4][2], b[2][2];
  f32x4 acc[8][4] = {};

#define READ_A(QM, buf)                                                        \
  do {                                                                         \
    _Pragma("unroll") for (int ii = 0; ii < 4; ++ii)                           \
        _Pragma("unroll") for (int s2 = 0; s2 < 2; ++s2)                       \
            a[ii][s2] = *reinterpret_cast<const bf16x8*>(                      \
                &lds[(buf) * 32768 + (QM) * 8192 + ii * 1024 + aE[s2]]);       \
  } while (0)
#define READ_B(QN, buf)                                                        \
  do {                                                                         \
    _Pragma("unroll") for (int jj = 0; jj < 2; ++jj)                           \
        _Pragma("unroll") for (int s2 = 0; s2 < 2; ++s2)                       \
            b[jj][s2] = *reinterpret_cast<const bf16x8*>(                      \
                &lds[(buf) * 32768 + 16384 + (QN) * 8192 + jj * 1024 +         \
                     bE[s2]]);                                                 \
  } while (0)
#define MMA(QM, QN)                                                            \
  do {                                                                         \
    __builtin_amdgcn_s_setprio(1);                                             \
    _Pragma("unroll") for (int s2 = 0; s2 < 2; ++s2)                           \
        _Pragma("unroll") for (int ii = 0; ii < 4; ++ii)                       \
            _Pragma("unroll") for (int jj = 0; jj < 2; ++jj)                   \
                acc[(QM) * 4 + ii][(QN) * 2 + jj] =                            \
                    __builtin_amdgcn_mfma_f32_16x16x32_bf16(                   \
                        a[ii][s2], b[jj][s2],                                  \
                        acc[(QM) * 4 + ii][(QN) * 2 + jj], 0, 0, 0);           \
    __builtin_amdgcn_s_setprio(0);                                             \
  } while (0)

  // ---- prologue: tile0 (buf0) fully + tile1 (buf1) {Ah0, Bh0, Ah1} ----
  STAGE_A(0, 0, 0); STAGE_B(0, 0, 0); STAGE_A(0, 1, 0); STAGE_B(0, 1, 0);
  FENCE();
  STAGE_A(1, 0, BK); STAGE_B(1, 0, BK); STAGE_A(1, 1, BK);
  FENCE();
  VMW(6);  // all 8 loads of tile0 landed; tile1's 6 may still be in flight
  __builtin_amdgcn_s_barrier();
  FENCE();

#pragma unroll 1
  for (int j = 0; j < NT2; ++j) {
    const int kt1 = j * 128 + 64;    // tile 2j+1
    const int kn0 = j * 128 + 128;   // tile 2j+2 -> buf0
    const int kn1 = j * 128 + 192;   // tile 2j+3 -> buf1
    const bool full = (j < NT2 - 1);

    // ---- P1: q(0,0) buf0 ----
    STAGE_B(1, 1, kt1);              // (2j+1).Bh1 (region free since prev P8)
    VMW(8);                          // guarantees (2j).Bh1 for P2
    READ_A(0, 0); READ_B(0, 0);
    PMID(); MMA(0, 0); PEND();

    // ---- P2: q(0,1) buf0 (A-frags reused) ----
    if (full) STAGE_A(0, 0, kn0);    // buf0.Ah0 last read in P1
    READ_B(1, 0);
    PMID(); MMA(0, 1); PEND();

    // ---- P3: q(1,0) buf0 ----
    READ_A(1, 0); READ_B(0, 0);
    PMID(); MMA(1, 0); PEND();

    // ---- P4: q(1,1) buf0 ----
    if (full) { STAGE_B(0, 0, kn0); STAGE_A(0, 1, kn0); VMW(8); }
    else      { VMW(2); }            // last iter: (2j+1) fully landed
    READ_B(1, 0);
    PMID(); MMA(1, 1); PEND();

    // ---- P5: q(0,0) buf1 ----
    if (full) { STAGE_B(0, 1, kn0); VMW(8); }
    else      { VMW(0); }            // last iter: drain (2j+1).Bh1
    READ_A(0, 1); READ_B(0, 1);
    PMID(); MMA(0, 0); PEND();

    // ---- P6: q(0,1) buf1 ----
    if (full) STAGE_A(1, 0, kn1);
    READ_B(1, 1);
    PMID(); MMA(0, 1); PEND();

    // ---- P7: q(1,0) buf1 ----
    READ_A(1, 1); READ_B(0, 1);
    PMID(); MMA(1, 0); PEND();

    // ---- P8: q(1,1) buf1 ----
    if (full) { STAGE_B(1, 0, kn1); STAGE_A(1, 1, kn1); VMW(8); }
    READ_B(1, 1);
    PMID(); MMA(1, 1); PEND();
  }

  // epilogue: C/D layout col = lane&15, row = (lane>>4)*4 + reg  [m89/m91]
#pragma unroll
  for (int i = 0; i < 8; ++i) {
    const int mb = m0 + (i >> 2) * 128 + wm * 64 + (i & 3) * 16 + kg * 4;
#pragma unroll
    for (int jn = 0; jn < 4; ++jn) {
      const int n = n0 + (jn >> 1) * 128 + wn * 32 + (jn & 1) * 16 + l15;
#pragma unroll
      for (int r = 0; r < 4; ++r) {
        out[(size_t)(mb + r) * Ndim + n] = acc[i][jn][r];
      }
    }
  }
#undef STAGE_A
#undef STAGE_B
#undef READ_A
#undef READ_B
#undef MMA
}

extern "C" void kernel_launch(void* const* d_in, const int* in_sizes, int n_in,
                              void* d_out, int out_size, void* d_ws, size_t ws_size,
                              hipStream_t stream) {
  const float* x  = (const float*)d_in[0];  // [4,2048,2048]
  const float* W  = (const float*)d_in[1];  // [2048,16,128]
  const float* A  = (const float*)d_in[2];  // [2048,4]
  const float* Bk = (const float*)d_in[3];  // [4,16,128]
  float* out = (float*)d_out;               // [4,2048,16,128] fp32

  uint16_t* Xb = (uint16_t*)d_ws;                               // 32 MB
  uint16_t* Wt = (uint16_t*)((char*)d_ws + (size_t)Mdim * Kdim * 2);  // 8 MB

  // fused: X fp32->bf16  +  Weff^T build
  prep_all<<<CVT_BLOCKS + PREP_BLOCKS, 256, 0, stream>>>(x, W, A, Bk, Xb, Wt);

  // main GEMM: 256 blocks (1/CU), 512 threads, 8-phase schedule
  gemm_8ph<<<(Mdim / BM) * (Ndim / BN), 512, 0, stream>>>(Xb, Wt, out);
}

// Round 2
// 194.257 us; speedup vs baseline: 1.0282x; 1.0150x over previous
//
#include <hip/hip_runtime.h>
#include <hip/hip_bf16.h>
#include <cstdint>

// Problem (all inputs/outputs fp32):
//   out[8192][2048] = X[8192][2048] @ Weff[2048][2048]
//   Weff[k][n] = W[k][n] + SCALE * sum_r A[k][r]*Bk[r][n], SCALE = 4/4 = 1.0
//
// Pipeline (2 launches):
//   prep_all: [blocks 0..8191] fp32 X -> bf16 Xb (d_ws)
//             [blocks 8192..9215] fp32 (W + A@Bk)^T -> bf16 Wt [N][K]
//   gemm_8ph: 256x256 tile, BK=64, 8 waves (2Mx4N), 8-phase schedule.
//
// R1 post-mortem: 73 us @ MfmaUtil 36%. LDS reads were 64/wave/iter
// (B re-read per M-quadrant) -> 6170 cyc/CU/iter LDS vs 4966 cyc MFMA:
// LDS-bound. Also 4 vmcnt waits/iter with only 1-3 phase slack.
// R2 changes:
//   * B-hoist: quadrant order q(0,0),(0,1),(1,1),(1,0); B(0),B(1) read
//     once per K-tile into b0/b1 and kept live -> 48 reads/iter (floor).
//   * m201-exact staging ledger: ONE half-tile staged per phase P2..P8
//     (P8 x2); steady-state waits ONLY VMW(6)@P4 and VMW(8)@P8, each
//     publishing (wait+barrier) half-tiles issued >=4 phases earlier.
//     Ledger (s_i = i-th stage of iter j, 2 loads each):
//       s1=P2 buf0.Bh0  s2=P3 buf0.Ah0  s3=P4 buf0.Bh1  s4=P5 buf0.Ah1
//       s5=P6 buf1.Bh0  s6=P7 buf1.Ah0  s7=P8 buf1.Bh1  s8=P8 buf1.Ah1
//     VMW(8)@P8 leaves {s5..s8} -> s1..s4 published for P1'..P3' reads.
//     VMW(6)@P4' (outstanding {s5..s8,s1',s2',s3'}=14) leaves {s1'..s3'}
//     -> s5..s8 published for P5'..P7' reads.
//     Region WAR safety: each region's last ds_read completes at its
//     phase's lgkmcnt(0)+PEND barrier, strictly before its stage phase.
//     Last iter: no stages; drains VMW(4)@P4, VMW(2)@P5, VMW(0)@P6
//     (each one phase before the consuming reads: publish = wait+barrier).
//   Round-4 lesson kept: do NOT read fp32 X inside the gemm.

using bf16 = __hip_bfloat16;
typedef __attribute__((ext_vector_type(8))) __bf16 bf16x8;
typedef __attribute__((ext_vector_type(4))) float f32x4;

constexpr int Mdim = 8192;   // B*S
constexpr int Ndim = 2048;   // NH*HD
constexpr int Kdim = 2048;   // H
constexpr float SCALE = 1.0f;  // ALPHA/RANK = 4/4

constexpr int BM = 256, BN = 256, BK = 64;
constexpr int NT2 = Kdim / (2 * BK);                   // 16 iterations
constexpr int CVT_BLOCKS = (Mdim * Kdim) / (256 * 8);  // 8192
constexpr int PREP_BLOCKS = (Ndim / 64) * (Kdim / 64); // 1024

__device__ __forceinline__ void gload_lds16(const void* g, void* l) {
  __builtin_amdgcn_global_load_lds(
      (const __attribute__((address_space(1))) uint32_t*)g,
      (__attribute__((address_space(3))) uint32_t*)l,
      16, 0, 0);
}

// ------------- prep_all: cvt_x (blocks<8192) + Weff^T build --------------
__global__ void prep_all(const float* __restrict__ X,
                         const float* __restrict__ W,
                         const float* __restrict__ A,
                         const float* __restrict__ Bk,
                         uint16_t* __restrict__ Xb,
                         uint16_t* __restrict__ Wt) {
  __shared__ float tile[64][65];  // used by prep part only (+1 pad)

  if (blockIdx.x < CVT_BLOCKS) {
    // ---- fp32 -> bf16, 8 elems/thread, float4 loads ----
    const int i = blockIdx.x * blockDim.x + threadIdx.x;
    const float4* Xv = (const float4*)X;
    float4 a = Xv[i * 2 + 0];
    float4 b = Xv[i * 2 + 1];
    uint16_t o[8];
    o[0] = __bfloat16_as_ushort(__float2bfloat16(a.x));
    o[1] = __bfloat16_as_ushort(__float2bfloat16(a.y));
    o[2] = __bfloat16_as_ushort(__float2bfloat16(a.z));
    o[3] = __bfloat16_as_ushort(__float2bfloat16(a.w));
    o[4] = __bfloat16_as_ushort(__float2bfloat16(b.x));
    o[5] = __bfloat16_as_ushort(__float2bfloat16(b.y));
    o[6] = __bfloat16_as_ushort(__float2bfloat16(b.z));
    o[7] = __bfloat16_as_ushort(__float2bfloat16(b.w));
    *reinterpret_cast<uint4*>(Xb + (size_t)i * 8) = *reinterpret_cast<uint4*>(o);
  } else {
    // ---- Weff^T = (W + A@Bk)^T, [N][K] bf16 ----
    const int pid = blockIdx.x - CVT_BLOCKS;       // 0..1023
    const int tx = threadIdx.x & 63;
    const int ty = threadIdx.x >> 6;
    const int n0 = (pid & 31) * 64, k0 = (pid >> 5) * 64;

    const int n = n0 + tx;
    const float b0 = Bk[0 * Ndim + n];
    const float b1 = Bk[1 * Ndim + n];
    const float b2 = Bk[2 * Ndim + n];
    const float b3 = Bk[3 * Ndim + n];

    for (int i = ty; i < 64; i += 4) {
      const int k = k0 + i;
      float w = W[(size_t)k * Ndim + n];
      w += SCALE * (A[k * 4 + 0] * b0 + A[k * 4 + 1] * b1 +
                    A[k * 4 + 2] * b2 + A[k * 4 + 3] * b3);
      tile[tx][i] = w;                       // transposed into LDS
    }
    __syncthreads();
    for (int i = ty; i < 64; i += 4) {
      Wt[(size_t)(n0 + i) * Kdim + (k0 + tx)] =
          __bfloat16_as_ushort(__float2bfloat16(tile[i][tx]));
    }
  }
}

// ---------------- main GEMM: C = Xb @ Weff (Wt is Weff^T, K-major) --------
#define FENCE() asm volatile("" ::: "memory")
#define VMW(N)  asm volatile("s_waitcnt vmcnt(" #N ")" ::: "memory")
#define LGKM8() asm volatile("s_waitcnt lgkmcnt(8)" ::: "memory")
#define PMID()                                                                 \
  do {                                                                         \
    FENCE();                                                                   \
    __builtin_amdgcn_s_barrier();                                              \
    asm volatile("s_waitcnt lgkmcnt(0)" ::: "memory");                         \
  } while (0)
#define PEND()                                                                 \
  do {                                                                         \
    FENCE();                                                                   \
    __builtin_amdgcn_s_barrier();                                              \
    FENCE();                                                                   \
  } while (0)

__global__ __launch_bounds__(512, 2) void gemm_8ph(
    const uint16_t* __restrict__ X, const uint16_t* __restrict__ Wt,
    float* __restrict__ out) {
  // LDS: [A0 | B0 | A1 | B1], 16384 uint16 each = 128 KiB total.
  __shared__ uint16_t lds[65536];

  const int t = threadIdx.x;
  const int wave = t >> 6, lane = t & 63;
  const int wm = wave >> 2, wn = wave & 3;   // 2 x 4 wave grid
  const int l15 = lane & 15, kg = lane >> 4;
  const int sw = l15 & 7;

  // Bijective XCD patch swizzle: 256 blocks, 8 XCDs x 32 blocks.
  const int lid = blockIdx.x;                 // 0..255
  const int xcd = lid & 7, loc = lid >> 3;    // loc 0..31
  const int by = xcd * 4 + (loc & 3);         // 0..31
  const int bx = loc >> 2;                    // 0..7
  const int m0 = by * BM, n0 = bx * BN;

  const uint16_t* Ag = X + (size_t)m0 * Kdim;
  const uint16_t* Bg = Wt + (size_t)n0 * Kdim;

  // staging geometry: slot = 8 rows x 64 cols (1 KB); wave w owns slots
  // {2w, 2w+1} of each 128-row half-tile. Source chunk col is XOR-swizzled
  // so the linear LDS dest holds phys chunk p = c ^ (row&7).
  const int r8 = lane >> 3;
  const int gc = (lane & 7) ^ r8;
  const int slot0 = wave * 2, slot1 = slot0 + 1;
  const size_t go0 = (size_t)(slot0 * 8 + r8) * Kdim + gc * 8;
  const size_t go1 = (size_t)(slot1 * 8 + r8) * Kdim + gc * 8;

  // per-lane LDS element offsets for frag reads (per k-step s2)
  int aE[2], bE[2];
#pragma unroll
  for (int s2 = 0; s2 < 2; ++s2) {
    const int p = (s2 * 4 + kg) ^ sw;
    aE[s2] = (wm * 64 + l15) * 64 + p * 8;
    bE[s2] = (wn * 32 + l15) * 64 + p * 8;
  }

#define STAGE_A(buf, h, kt)                                                    \
  do {                                                                         \
    gload_lds16(Ag + go0 + (size_t)(h) * 128 * Kdim + (kt),                    \
                &lds[(buf) * 32768 + (h) * 8192 + slot0 * 512]);               \
    gload_lds16(Ag + go1 + (size_t)(h) * 128 * Kdim + (kt),                    \
                &lds[(buf) * 32768 + (h) * 8192 + slot1 * 512]);               \
  } while (0)
#define STAGE_B(buf, h, kt)                                                    \
  do {                                                                         \
    gload_lds16(Bg + go0 + (size_t)(h) * 128 * Kdim + (kt),                    \
                &lds[(buf) * 32768 + 16384 + (h) * 8192 + slot0 * 512]);       \
    gload_lds16(Bg + go1 + (size_t)(h) * 128 * Kdim + (kt),                    \
                &lds[(buf) * 32768 + 16384 + (h) * 8192 + slot1 * 512]);       \
  } while (0)

  bf16x8 a[4][2], b0[2][2], b1[2][2];
  f32x4 acc[8][4] = {};

#define READ_A(QM, buf)                                                        \
  do {                                                                         \
    _Pragma("unroll") for (int ii = 0; ii < 4; ++ii)                           \
        _Pragma("unroll") for (int s2 = 0; s2 < 2; ++s2)                       \
            a[ii][s2] = *reinterpret_cast<const bf16x8*>(                      \
                &lds[(buf) * 32768 + (QM) * 8192 + ii * 1024 + aE[s2]]);       \
  } while (0)
#define READ_B(QN, buf, dst)                                                   \
  do {                                                                         \
    _Pragma("unroll") for (int jj = 0; jj < 2; ++jj)                           \
        _Pragma("unroll") for (int s2 = 0; s2 < 2; ++s2)                       \
            dst[jj][s2] = *reinterpret_cast<const bf16x8*>(                    \
                &lds[(buf) * 32768 + 16384 + (QN) * 8192 + jj * 1024 +         \
                     bE[s2]]);                                                 \
  } while (0)
#define MMA(QM, QN, barr)                                                      \
  do {                                                                         \
    __builtin_amdgcn_s_setprio(1);                                             \
    _Pragma("unroll") for (int s2 = 0; s2 < 2; ++s2)                           \
        _Pragma("unroll") for (int ii = 0; ii < 4; ++ii)                       \
            _Pragma("unroll") for (int jj = 0; jj < 2; ++jj)                   \
                acc[(QM) * 4 + ii][(QN) * 2 + jj] =                            \
                    __builtin_amdgcn_mfma_f32_16x16x32_bf16(                   \
                        a[ii][s2], barr[jj][s2],                               \
                        acc[(QM) * 4 + ii][(QN) * 2 + jj], 0, 0, 0);           \
    __builtin_amdgcn_s_setprio(0);                                             \
  } while (0)

  // ---- prologue: tile0 -> buf0 (z1..z4), tile1 -> buf1 (z5..z8) ----
  STAGE_B(0, 0, 0); STAGE_A(0, 0, 0); STAGE_B(0, 1, 0); STAGE_A(0, 1, 0);
  FENCE();
  STAGE_B(1, 0, BK); STAGE_A(1, 0, BK); STAGE_B(1, 1, BK); STAGE_A(1, 1, BK);
  FENCE();
  VMW(8);  // tile0 fully landed; tile1's 8 loads may stay in flight
  __builtin_amdgcn_s_barrier();
  FENCE();

#pragma unroll 1
  for (int j = 0; j < NT2; ++j) {
    const int kn0 = j * 128 + 128;   // tile 2j+2 -> buf0
    const int kn1 = j * 128 + 192;   // tile 2j+3 -> buf1
    const bool full = (j < NT2 - 1);

    // ---- P1: q(0,0) buf0 [12 reads] ----
    READ_A(0, 0); READ_B(0, 0, b0);
    LGKM8();
    PMID(); MMA(0, 0, b0); PEND();

    // ---- P2: q(0,1) buf0 [4 reads] ----
    READ_B(1, 0, b1);
    if (full) STAGE_B(0, 0, kn0);          // s1
    PMID(); MMA(0, 1, b1); PEND();

    // ---- P3: q(1,1) buf0 [8 reads] ----
    READ_A(1, 0);
    if (full) STAGE_A(0, 0, kn0);          // s2
    PMID(); MMA(1, 1, b1); PEND();

    // ---- P4: q(1,0) buf0 [0 reads] ----
    if (full) { STAGE_B(0, 1, kn0); VMW(6); }   // s3; publish prev s5..s8
    else      { VMW(4); }                       // publish s5,s6 for P5
    PMID(); MMA(1, 0, b0); PEND();

    // ---- P5: q(0,0) buf1 [12 reads] ----
    READ_A(0, 1); READ_B(0, 1, b0);
    if (full) STAGE_A(0, 1, kn0);          // s4
    else      VMW(2);                      // publish s7 for P6
    LGKM8();
    PMID(); MMA(0, 0, b0); PEND();

    // ---- P6: q(0,1) buf1 [4 reads] ----
    READ_B(1, 1, b1);
    if (full) STAGE_B(1, 0, kn1);          // s5
    else      VMW(0);                      // publish s8 for P7
    PMID(); MMA(0, 1, b1); PEND();

    // ---- P7: q(1,1) buf1 [8 reads] ----
    READ_A(1, 1);
    if (full) STAGE_A(1, 0, kn1);          // s6
    PMID(); MMA(1, 1, b1); PEND();

    // ---- P8: q(1,0) buf1 [0 reads] ----
    if (full) { STAGE_B(1, 1, kn1); STAGE_A(1, 1, kn1); VMW(8); }  // s7,s8
    PMID(); MMA(1, 0, b0); PEND();
  }

  // epilogue: C/D layout col = lane&15, row = (lane>>4)*4 + reg  [m89/m91]
#pragma unroll
  for (int i = 0; i < 8; ++i) {
    const int mb = m0 + (i >> 2) * 128 + wm * 64 + (i & 3) * 16 + kg * 4;
#pragma unroll
    for (int jn = 0; jn < 4; ++jn) {
      const int n = n0 + (jn >> 1) * 128 + wn * 32 + (jn & 1) * 16 + l15;
#pragma unroll
      for (int r = 0; r < 4; ++r) {
        out[(size_t)(mb + r) * Ndim + n] = acc[i][jn][r];
      }
    }
  }
#undef STAGE_A
#undef STAGE_B
#undef READ_A
#undef READ_B
#undef MMA
}

extern "C" void kernel_launch(void* const* d_in, const int* in_sizes, int n_in,
                              void* d_out, int out_size, void* d_ws, size_t ws_size,
                              hipStream_t stream) {
  const float* x  = (const float*)d_in[0];  // [4,2048,2048]
  const float* W  = (const float*)d_in[1];  // [2048,16,128]
  const float* A  = (const float*)d_in[2];  // [2048,4]
  const float* Bk = (const float*)d_in[3];  // [4,16,128]
  float* out = (float*)d_out;               // [4,2048,16,128] fp32

  uint16_t* Xb = (uint16_t*)d_ws;                               // 32 MB
  uint16_t* Wt = (uint16_t*)((char*)d_ws + (size_t)Mdim * Kdim * 2);  // 8 MB

  // fused: X fp32->bf16  +  Weff^T build
  prep_all<<<CVT_BLOCKS + PREP_BLOCKS, 256, 0, stream>>>(x, W, A, Bk, Xb, Wt);

  // main GEMM: 256 blocks (1/CU), 512 threads, 8-phase schedule
  gemm_8ph<<<(Mdim / BM) * (Ndim / BN), 512, 0, stream>>>(Xb, Wt, out);
}

// Round 3
// 190.732 us; speedup vs baseline: 1.0472x; 1.0185x over previous
//
#include <hip/hip_runtime.h>
#include <hip/hip_bf16.h>
#include <cstdint>

// Problem (all inputs/outputs fp32):
//   out[8192][2048] = X[8192][2048] @ Weff[2048][2048]
//   Weff[k][n] = W[k][n] + SCALE * sum_r A[k][r]*Bk[r][n], SCALE = 4/4 = 1.0
//
// Pipeline (2 launches):
//   prep_all: [blocks 0..8191] fp32 X -> bf16 Xb (d_ws)
//             [blocks 8192..9215] fp32 (W + A@Bk)^T -> bf16 Wt [N][K]
//   gemm_8ph: 256x256 tile, BK=64, 8 waves (2Mx4N), 8-phase schedule.
//
// R2 post-mortem: read-count cut (64->48/wave/iter) moved nothing ->
// steady state is NOT LDS-read-bound. Budget closure: MFMA-busy 65.5k cyc
// (36%), steady @ m201 rate ~105k cyc, and ~40k cyc of UN-OVERLAPPED
// epilogue drain: all 256 blocks lockstep (1 block/CU), 64 MB fp32 C
// written in one synchronized burst after the last MFMA. R0's 128² kernel
// overlapped the drain via 4 blocks/CU -- that's why 8ph gained nothing
// end-to-end. Also: VGPR budget saturated (128 arch + 128 acc = 256/wave,
// the 2-waves/SIMD cliff) -> no register-based prefetch possible.
// R3: peel the final iteration; issue each quadrant's stores right after
// its last MFMA phase (q00@P5, q01@P6, q11@P7, q10@P8). Stores count in
// vmcnt, so the peeled iter does ONE VMW(0)@P4 (loads issued >=4 phases
// earlier -> free) and NO vm-waits after stores begin. Steady loop is now
// branch-free (full iterations only, j=0..NT2-2).
//   Steady ledger (s_i = i-th stage of iter j, 2 loads each):
//     s1=P2 buf0.Bh0  s2=P3 buf0.Ah0  s3=P4 buf0.Bh1  s4=P5 buf0.Ah1
//     s5=P6 buf1.Bh0  s6=P7 buf1.Ah0  s7=P8 buf1.Bh1  s8=P8 buf1.Ah1
//   VMW(6)@P4 drains prev s5..s8 (published for P5..P8 reads);
//   VMW(8)@P8 drains s1..s4 (published for next P1..P4 reads).
//   Region WAR safety: each region's last ds_read completes at its phase's
//   lgkmcnt(0)+PEND barrier, strictly before its staging phase.
//   Round-4 lesson kept: do NOT read fp32 X inside the gemm.

using bf16 = __hip_bfloat16;
typedef __attribute__((ext_vector_type(8))) __bf16 bf16x8;
typedef __attribute__((ext_vector_type(4))) float f32x4;

constexpr int Mdim = 8192;   // B*S
constexpr int Ndim = 2048;   // NH*HD
constexpr int Kdim = 2048;   // H
constexpr float SCALE = 1.0f;  // ALPHA/RANK = 4/4

constexpr int BM = 256, BN = 256, BK = 64;
constexpr int NT2 = Kdim / (2 * BK);                   // 16 iterations
constexpr int CVT_BLOCKS = (Mdim * Kdim) / (256 * 8);  // 8192
constexpr int PREP_BLOCKS = (Ndim / 64) * (Kdim / 64); // 1024

__device__ __forceinline__ void gload_lds16(const void* g, void* l) {
  __builtin_amdgcn_global_load_lds(
      (const __attribute__((address_space(1))) uint32_t*)g,
      (__attribute__((address_space(3))) uint32_t*)l,
      16, 0, 0);
}

// ------------- prep_all: cvt_x (blocks<8192) + Weff^T build --------------
__global__ void prep_all(const float* __restrict__ X,
                         const float* __restrict__ W,
                         const float* __restrict__ A,
                         const float* __restrict__ Bk,
                         uint16_t* __restrict__ Xb,
                         uint16_t* __restrict__ Wt) {
  __shared__ float tile[64][65];  // used by prep part only (+1 pad)

  if (blockIdx.x < CVT_BLOCKS) {
    // ---- fp32 -> bf16, 8 elems/thread, float4 loads ----
    const int i = blockIdx.x * blockDim.x + threadIdx.x;
    const float4* Xv = (const float4*)X;
    float4 a = Xv[i * 2 + 0];
    float4 b = Xv[i * 2 + 1];
    uint16_t o[8];
    o[0] = __bfloat16_as_ushort(__float2bfloat16(a.x));
    o[1] = __bfloat16_as_ushort(__float2bfloat16(a.y));
    o[2] = __bfloat16_as_ushort(__float2bfloat16(a.z));
    o[3] = __bfloat16_as_ushort(__float2bfloat16(a.w));
    o[4] = __bfloat16_as_ushort(__float2bfloat16(b.x));
    o[5] = __bfloat16_as_ushort(__float2bfloat16(b.y));
    o[6] = __bfloat16_as_ushort(__float2bfloat16(b.z));
    o[7] = __bfloat16_as_ushort(__float2bfloat16(b.w));
    *reinterpret_cast<uint4*>(Xb + (size_t)i * 8) = *reinterpret_cast<uint4*>(o);
  } else {
    // ---- Weff^T = (W + A@Bk)^T, [N][K] bf16 ----
    const int pid = blockIdx.x - CVT_BLOCKS;       // 0..1023
    const int tx = threadIdx.x & 63;
    const int ty = threadIdx.x >> 6;
    const int n0 = (pid & 31) * 64, k0 = (pid >> 5) * 64;

    const int n = n0 + tx;
    const float b0 = Bk[0 * Ndim + n];
    const float b1 = Bk[1 * Ndim + n];
    const float b2 = Bk[2 * Ndim + n];
    const float b3 = Bk[3 * Ndim + n];

    for (int i = ty; i < 64; i += 4) {
      const int k = k0 + i;
      float w = W[(size_t)k * Ndim + n];
      w += SCALE * (A[k * 4 + 0] * b0 + A[k * 4 + 1] * b1 +
                    A[k * 4 + 2] * b2 + A[k * 4 + 3] * b3);
      tile[tx][i] = w;                       // transposed into LDS
    }
    __syncthreads();
    for (int i = ty; i < 64; i += 4) {
      Wt[(size_t)(n0 + i) * Kdim + (k0 + tx)] =
          __bfloat16_as_ushort(__float2bfloat16(tile[i][tx]));
    }
  }
}

// ---------------- main GEMM: C = Xb @ Weff (Wt is Weff^T, K-major) --------
#define FENCE() asm volatile("" ::: "memory")
#define VMW(N)  asm volatile("s_waitcnt vmcnt(" #N ")" ::: "memory")
#define LGKM8() asm volatile("s_waitcnt lgkmcnt(8)" ::: "memory")
#define PMID()                                                                 \
  do {                                                                         \
    FENCE();                                                                   \
    __builtin_amdgcn_s_barrier();                                              \
    asm volatile("s_waitcnt lgkmcnt(0)" ::: "memory");                         \
  } while (0)
#define PEND()                                                                 \
  do {                                                                         \
    FENCE();                                                                   \
    __builtin_amdgcn_s_barrier();                                              \
    FENCE();                                                                   \
  } while (0)

__global__ __launch_bounds__(512, 2) void gemm_8ph(
    const uint16_t* __restrict__ X, const uint16_t* __restrict__ Wt,
    float* __restrict__ out) {
  // LDS: [A0 | B0 | A1 | B1], 16384 uint16 each = 128 KiB total.
  __shared__ uint16_t lds[65536];

  const int t = threadIdx.x;
  const int wave = t >> 6, lane = t & 63;
  const int wm = wave >> 2, wn = wave & 3;   // 2 x 4 wave grid
  const int l15 = lane & 15, kg = lane >> 4;
  const int sw = l15 & 7;

  // Bijective XCD patch swizzle: 256 blocks, 8 XCDs x 32 blocks.
  const int lid = blockIdx.x;                 // 0..255
  const int xcd = lid & 7, loc = lid >> 3;    // loc 0..31
  const int by = xcd * 4 + (loc & 3);         // 0..31
  const int bx = loc >> 2;                    // 0..7
  const int m0 = by * BM, n0 = bx * BN;

  const uint16_t* Ag = X + (size_t)m0 * Kdim;
  const uint16_t* Bg = Wt + (size_t)n0 * Kdim;

  // staging geometry: slot = 8 rows x 64 cols (1 KB); wave w owns slots
  // {2w, 2w+1} of each 128-row half-tile. Source chunk col is XOR-swizzled
  // so the linear LDS dest holds phys chunk p = c ^ (row&7).
  const int r8 = lane >> 3;
  const int gc = (lane & 7) ^ r8;
  const int slot0 = wave * 2, slot1 = slot0 + 1;
  const size_t go0 = (size_t)(slot0 * 8 + r8) * Kdim + gc * 8;
  const size_t go1 = (size_t)(slot1 * 8 + r8) * Kdim + gc * 8;

  // per-lane LDS element offsets for frag reads (per k-step s2)
  int aE[2], bE[2];
#pragma unroll
  for (int s2 = 0; s2 < 2; ++s2) {
    const int p = (s2 * 4 + kg) ^ sw;
    aE[s2] = (wm * 64 + l15) * 64 + p * 8;
    bE[s2] = (wn * 32 + l15) * 64 + p * 8;
  }

#define STAGE_A(buf, h, kt)                                                    \
  do {                                                                         \
    gload_lds16(Ag + go0 + (size_t)(h) * 128 * Kdim + (kt),                    \
                &lds[(buf) * 32768 + (h) * 8192 + slot0 * 512]);               \
    gload_lds16(Ag + go1 + (size_t)(h) * 128 * Kdim + (kt),                    \
                &lds[(buf) * 32768 + (h) * 8192 + slot1 * 512]);               \
  } while (0)
#define STAGE_B(buf, h, kt)                                                    \
  do {                                                                         \
    gload_lds16(Bg + go0 + (size_t)(h) * 128 * Kdim + (kt),                    \
                &lds[(buf) * 32768 + 16384 + (h) * 8192 + slot0 * 512]);       \
    gload_lds16(Bg + go1 + (size_t)(h) * 128 * Kdim + (kt),                    \
                &lds[(buf) * 32768 + 16384 + (h) * 8192 + slot1 * 512]);       \
  } while (0)

  bf16x8 a[4][2], b0[2][2], b1[2][2];
  f32x4 acc[8][4] = {};

#define READ_A(QM, buf)                                                        \
  do {                                                                         \
    _Pragma("unroll") for (int ii = 0; ii < 4; ++ii)                           \
        _Pragma("unroll") for (int s2 = 0; s2 < 2; ++s2)                       \
            a[ii][s2] = *reinterpret_cast<const bf16x8*>(                      \
                &lds[(buf) * 32768 + (QM) * 8192 + ii * 1024 + aE[s2]]);       \
  } while (0)
#define READ_B(QN, buf, dst)                                                   \
  do {                                                                         \
    _Pragma("unroll") for (int jj = 0; jj < 2; ++jj)                           \
        _Pragma("unroll") for (int s2 = 0; s2 < 2; ++s2)                       \
            dst[jj][s2] = *reinterpret_cast<const bf16x8*>(                    \
                &lds[(buf) * 32768 + 16384 + (QN) * 8192 + jj * 1024 +         \
                     bE[s2]]);                                                 \
  } while (0)
#define MMA(QM, QN, barr)                                                      \
  do {                                                                         \
    __builtin_amdgcn_s_setprio(1);                                             \
    _Pragma("unroll") for (int s2 = 0; s2 < 2; ++s2)                           \
        _Pragma("unroll") for (int ii = 0; ii < 4; ++ii)                       \
            _Pragma("unroll") for (int jj = 0; jj < 2; ++jj)                   \
                acc[(QM) * 4 + ii][(QN) * 2 + jj] =                            \
                    __builtin_amdgcn_mfma_f32_16x16x32_bf16(                   \
                        a[ii][s2], barr[jj][s2],                               \
                        acc[(QM) * 4 + ii][(QN) * 2 + jj], 0, 0, 0);           \
    __builtin_amdgcn_s_setprio(0);                                             \
  } while (0)
// store one 128x128 output quadrant (this wave's 64x32 piece of it)
#define STORE_Q(QM, QN)                                                        \
  do {                                                                         \
    _Pragma("unroll") for (int ii = 0; ii < 4; ++ii) {                         \
      const int mb = m0 + (QM) * 128 + wm * 64 + ii * 16 + kg * 4;             \
      _Pragma("unroll") for (int jj = 0; jj < 2; ++jj) {                       \
        const int n = n0 + (QN) * 128 + wn * 32 + jj * 16 + l15;               \
        _Pragma("unroll") for (int r = 0; r < 4; ++r)                          \
            out[(size_t)(mb + r) * Ndim + n] =                                 \
                acc[(QM) * 4 + ii][(QN) * 2 + jj][r];                          \
      }                                                                        \
    }                                                                          \
  } while (0)

  // ---- prologue: tile0 -> buf0, tile1 -> buf1 ----
  STAGE_B(0, 0, 0); STAGE_A(0, 0, 0); STAGE_B(0, 1, 0); STAGE_A(0, 1, 0);
  FENCE();
  STAGE_B(1, 0, BK); STAGE_A(1, 0, BK); STAGE_B(1, 1, BK); STAGE_A(1, 1, BK);
  FENCE();
  VMW(8);  // tile0 fully landed; tile1's 8 loads may stay in flight
  __builtin_amdgcn_s_barrier();
  FENCE();

  // ---- steady loop: branch-free full iterations, j = 0 .. NT2-2 ----
#pragma unroll 1
  for (int j = 0; j < NT2 - 1; ++j) {
    const int kn0 = j * 128 + 128;   // tile 2j+2 -> buf0
    const int kn1 = j * 128 + 192;   // tile 2j+3 -> buf1

    // ---- P1: q(0,0) buf0 [12 reads] ----
    READ_A(0, 0); READ_B(0, 0, b0);
    LGKM8();
    PMID(); MMA(0, 0, b0); PEND();

    // ---- P2: q(0,1) buf0 [4 reads] ----
    READ_B(1, 0, b1);
    STAGE_B(0, 0, kn0);                    // s1
    PMID(); MMA(0, 1, b1); PEND();

    // ---- P3: q(1,1) buf0 [8 reads] ----
    READ_A(1, 0);
    STAGE_A(0, 0, kn0);                    // s2
    PMID(); MMA(1, 1, b1); PEND();

    // ---- P4: q(1,0) buf0 [0 reads] ----
    STAGE_B(0, 1, kn0); VMW(6);            // s3; publish prev s5..s8
    PMID(); MMA(1, 0, b0); PEND();

    // ---- P5: q(0,0) buf1 [12 reads] ----
    READ_A(0, 1); READ_B(0, 1, b0);
    STAGE_A(0, 1, kn0);                    // s4
    LGKM8();
    PMID(); MMA(0, 0, b0); PEND();

    // ---- P6: q(0,1) buf1 [4 reads] ----
    READ_B(1, 1, b1);
    STAGE_B(1, 0, kn1);                    // s5
    PMID(); MMA(0, 1, b1); PEND();

    // ---- P7: q(1,1) buf1 [8 reads] ----
    READ_A(1, 1);
    STAGE_A(1, 0, kn1);                    // s6
    PMID(); MMA(1, 1, b1); PEND();

    // ---- P8: q(1,0) buf1 [0 reads] ----
    STAGE_B(1, 1, kn1); STAGE_A(1, 1, kn1); VMW(8);  // s7,s8; publish s1..s4
    PMID(); MMA(1, 0, b0); PEND();
  }

  // ---- peeled final iteration (tiles 30/31): no staging; stores overlap ----
  // P1: q(0,0) buf0
  READ_A(0, 0); READ_B(0, 0, b0);
  LGKM8();
  PMID(); MMA(0, 0, b0); PEND();
  // P2: q(0,1) buf0
  READ_B(1, 0, b1);
  PMID(); MMA(0, 1, b1); PEND();
  // P3: q(1,1) buf0
  READ_A(1, 0);
  PMID(); MMA(1, 1, b1); PEND();
  // P4: q(1,0) buf0 — single full drain; publishes buf1 (s5..s8, issued
  // >=4 phases ago -> free). No vm-waits after this point: stores follow.
  VMW(0);
  PMID(); MMA(1, 0, b0); PEND();
  // P5: q(0,0) buf1 — last touch of q(0,0): store it after the MMA.
  READ_A(0, 1); READ_B(0, 1, b0);
  LGKM8();
  PMID(); MMA(0, 0, b0); STORE_Q(0, 0); PEND();
  // P6: q(0,1) buf1 — store q(0,1)
  READ_B(1, 1, b1);
  PMID(); MMA(0, 1, b1); STORE_Q(0, 1); PEND();
  // P7: q(1,1) buf1 — store q(1,1)
  READ_A(1, 1);
  PMID(); MMA(1, 1, b1); STORE_Q(1, 1); PEND();
  // P8: q(1,0) buf1 — store q(1,0); kernel end waits for store retirement.
  PMID(); MMA(1, 0, b0); STORE_Q(1, 0);

#undef STAGE_A
#undef STAGE_B
#undef READ_A
#undef READ_B
#undef MMA
#undef STORE_Q
}

extern "C" void kernel_launch(void* const* d_in, const int* in_sizes, int n_in,
                              void* d_out, int out_size, void* d_ws, size_t ws_size,
                              hipStream_t stream) {
  const float* x  = (const float*)d_in[0];  // [4,2048,2048]
  const float* W  = (const float*)d_in[1];  // [2048,16,128]
  const float* A  = (const float*)d_in[2];  // [2048,4]
  const float* Bk = (const float*)d_in[3];  // [4,16,128]
  float* out = (float*)d_out;               // [4,2048,16,128] fp32

  uint16_t* Xb = (uint16_t*)d_ws;                               // 32 MB
  uint16_t* Wt = (uint16_t*)((char*)d_ws + (size_t)Mdim * Kdim * 2);  // 8 MB

  // fused: X fp32->bf16  +  Weff^T build
  prep_all<<<CVT_BLOCKS + PREP_BLOCKS, 256, 0, stream>>>(x, W, A, Bk, Xb, Wt);

  // main GEMM: 256 blocks (1/CU), 512 threads, 8-phase schedule
  gemm_8ph<<<(Mdim / BM) * (Ndim / BN), 512, 0, stream>>>(Xb, Wt, out);
}